// Round 7
// baseline (246.716 us; speedup 1.0000x reference)
//
#include <hip/hip_runtime.h>
#include <stdint.h>
#include <stddef.h>

// ==== JAX threefry mode: 1 = jax_threefry_partitionable (default in modern JAX)
#define JAX_PARTITIONABLE 1

#define B_   256
#define N_   512
#define NP_  513     // N+1
#define KROW 516     // padded key row stride (floats), 16B-aligned
#define T_   64
#define CS   4       // sampling chunk size (steps)
#define NCH  16      // T_/CS
#define NEGC 1e9f

// ---------------- threefry2x32 (matches jax/_src/prng.py) ----------------
__host__ __device__ __forceinline__ void tf2x32(uint32_t k0, uint32_t k1,
    uint32_t x0, uint32_t x1, uint32_t& o0, uint32_t& o1) {
  const uint32_t k2 = k0 ^ k1 ^ 0x1BD11BDAu;
#define TFR(r) { x0 += x1; x1 = (x1 << (r)) | (x1 >> (32 - (r))); x1 ^= x0; }
  x0 += k0; x1 += k1;
  TFR(13) TFR(15) TFR(26) TFR(6)
  x0 += k1; x1 += k2 + 1u;
  TFR(17) TFR(29) TFR(16) TFR(24)
  x0 += k2; x1 += k0 + 2u;
  TFR(13) TFR(15) TFR(26) TFR(6)
  x0 += k0; x1 += k1 + 3u;
  TFR(17) TFR(29) TFR(16) TFR(24)
  x0 += k1; x1 += k2 + 4u;
  TFR(13) TFR(15) TFR(26) TFR(6)
  x0 += k2; x1 += k0 + 5u;
#undef TFR
  o0 = x0; o1 = x1;
}

struct SkKeys { uint32_t k[128]; };

static SkKeys compute_chain() {
  SkKeys s;
  uint32_t r0 = 0u, r1 = 42u;   // jax.random.key(42)
  for (int t = 0; t < 64; ++t) {
#if JAX_PARTITIONABLE
    uint32_t a0, a1, b0, b1;
    tf2x32(r0, r1, 0u, 0u, a0, a1);
    tf2x32(r0, r1, 0u, 1u, b0, b1);
    s.k[2*t] = b0; s.k[2*t+1] = b1;
    r0 = a0; r1 = a1;
#else
    uint32_t p0, p1, q0, q1;
    tf2x32(r0, r1, 0u, 2u, p0, p1);
    tf2x32(r0, r1, 1u, 3u, q0, q1);
    s.k[2*t] = p1; s.k[2*t+1] = q1;
    r0 = p0; r1 = q0;
#endif
  }
  return s;
}

__device__ __forceinline__ float gumbel_draw(uint32_t k0, uint32_t k1, int b, int n) {
  uint32_t bits;
#if JAX_PARTITIONABLE
  uint32_t j = (uint32_t)(b * NP_ + n);
  uint32_t o0, o1; tf2x32(k0, k1, 0u, j, o0, o1);
  bits = o0 ^ o1;
#else
  int j = b * NP_ + n;
  uint32_t o0, o1;
  if (j < 65664) { tf2x32(k0, k1, (uint32_t)j, (uint32_t)(j + 65664), o0, o1); bits = o0; }
  else           { tf2x32(k0, k1, (uint32_t)(j - 65664), (uint32_t)j, o0, o1); bits = o1; }
#endif
  float f = __uint_as_float((bits >> 9) | 0x3F800000u) - 1.0f;
  const float TINY = 1.17549435e-38f;
  float u = fmaxf(TINY, f + TINY);
  return -logf(-logf(u));
}

__device__ __forceinline__ float sigm(float x) {
  return 0.5f + 0.5f * tanhf(0.5f * x);   // XLA logistic
}

// barrier with LDS-only drain (no vmcnt: global stores never read back)
__device__ __forceinline__ void bar_lds() {
  asm volatile("s_waitcnt lgkmcnt(0)\n\ts_barrier" ::: "memory");
}
__device__ __forceinline__ void lds_fence() {
  asm volatile("s_waitcnt lgkmcnt(0)" ::: "memory");
}

// ---------------- LDS layout (floats) ----------------
#define OFF_KEY   0        // 32*516 = 16512, c-major [32][516]
#define OFF_H     16512    // 64*32 = 2048
#define OFF_Q     18560    // 2 slots * 2064 = 4128
#define OFF_G     22688    // 3 slots * 2064 = 6192
#define OFF_UNITS 28880    // 516
#define OFF_LNH   29396    // 128
#define OFF_T     29524    // 256
#define OFF_X0    29780    // 32
#define OFF_ES    29812    // 32
#define OFF_PART  29844    // 512
#define OFF_FLAGA 30356    // 64 ints (aliased)
#define OFF_FLAGB 30420    // 64 ints
#define OFF_CTRT  30484    // 1 int
#define LDS_FLOATS 30488   // 121,952 B

__global__ void __launch_bounds__(512, 2)
suh_fused(const float* __restrict__ emb, const float* __restrict__ autm,
          const float* __restrict__ aum, const float* __restrict__ ent,
          const float* __restrict__ temp_p,
          const float* __restrict__ key_w, const float* __restrict__ key_b,
          const float* __restrict__ func_w, const float* __restrict__ func_b,
          const float* __restrict__ fc1_w, const float* __restrict__ fc1_b,
          const float* __restrict__ fc2_w, const float* __restrict__ fc2_b,
          const float* __restrict__ emb_w, const float* __restrict__ emb_b,
          const float* __restrict__ wx, const float* __restrict__ wh,
          const float* __restrict__ lstm_bb,
          const float* __restrict__ ln_gx, const float* __restrict__ ln_bx,
          const float* __restrict__ ln_gh, const float* __restrict__ ln_bh,
          float* __restrict__ out_logits, float* __restrict__ out_valid,
          float* __restrict__ out_units, float* __restrict__ out_final,
          SkKeys sk)
{
  extern __shared__ __align__(16) float sm[];
  int* smi = (int*)sm;
  volatile int* vsmi = (volatile int*)sm;
  const int b   = blockIdx.x;
  const int tid = threadIdx.x;
  const int L   = tid - 64;          // pipeline worker lane id (tid >= 64)

  const float temp = temp_p[0];

  // ---- init flags/counters, then one cheap barrier ----
  if (tid < 64)        smi[OFF_FLAGB + tid] = 0;
  else if (tid < 128)  smi[OFF_FLAGA + (tid - 64)] = 0;
  else if (tid == 128) smi[OFF_CTRT] = 0;
  __syncthreads();                                   // bar1 (instant)

  // persistent sampling state (wave0) / key columns (pipeline workers)
  float kr0[32], kr1[32];
  float mreg[8], ureg[8];
  float m512 = 1.0f;
  int done_reg = 0;

  if (tid < 256) {
    // ======== P0: T = relu(emb@fc1+b1) + relu(autm@func+fb) — waves 0-3 ========
    {
      float a = 0.f;
      const float* e = emb + (size_t)b * 1024;
      #pragma unroll 8
      for (int k = 0; k < 1024; ++k) a += e[k] * fc1_w[k * 256 + tid];
      a = fmaxf(a + fc1_b[tid], 0.f);
      float f = 0.f;
      const float* m = autm + (size_t)b * 259;
      for (int k = 0; k < 259; ++k) f += m[k] * func_w[k * 256 + tid];
      f = fmaxf(f + func_b[tid], 0.f);
      sm[OFF_T + tid] = a + f;
    }
    lds_fence();
    if ((tid & 63) == 0) atomicAdd(&smi[OFF_CTRT], 1);

    if (tid < 64) {
      // ======== wave0: P1 (x0) then beta gx-side ========
      while (vsmi[OFF_CTRT] != 4) __builtin_amdgcn_s_sleep(1);
      if (tid < 32) {
        float s = 0.f;
        #pragma unroll 8
        for (int m2 = 0; m2 < 256; ++m2) s += sm[OFF_T + m2] * fc2_w[m2 * 32 + tid];
        sm[OFF_X0 + tid] = fmaxf(s + fc2_b[tid], 0.f);
      }
      // wx columns tid, tid+64 in registers (r4-proven 64-reg budget)
      float wxr0[32], wxr1[32];
      #pragma unroll
      for (int k = 0; k < 32; ++k) {
        wxr0[k] = wx[k * 128 + tid];
        wxr1[k] = wx[k * 128 + 64 + tid];
      }
      #pragma unroll
      for (int k = 0; k < 32; ++k) asm volatile("" : "+v"(wxr0[k]), "+v"(wxr1[k]));
      const float gxg0 = ln_gx[tid], gxg1 = ln_gx[tid + 64];
      const float gxb0 = ln_bx[tid], gxb1 = ln_bx[tid + 64];
      const float lb0  = lstm_bb[tid], lb1 = lstm_bb[tid + 64];

      float xf[32];
      #pragma unroll
      for (int r = 0; r < 8; ++r) {
        float4 v = *(const float4*)&sm[OFF_X0 + r * 4];
        xf[r*4] = v.x; xf[r*4+1] = v.y; xf[r*4+2] = v.z; xf[r*4+3] = v.w;
      }
      float creg = 0.f;

      #pragma unroll 1
      for (int t = 0; t < T_; ++t) {
        float a0 = 0.f, a1 = 0.f;
        #pragma unroll
        for (int k = 0; k < 32; ++k) { a0 += xf[k] * wxr0[k]; a1 += xf[k] * wxr1[k]; }
        float sx = a0 + a1;
        for (int off = 32; off; off >>= 1) sx += __shfl_down(sx, off);
        float mx = __shfl(sx, 0) * (1.0f / 128.0f);
        float dx0 = a0 - mx, dx1 = a1 - mx;
        float ssx = dx0 * dx0 + dx1 * dx1;
        for (int off = 32; off; off >>= 1) ssx += __shfl_down(ssx, off);
        float vx = __shfl(ssx, 0) * (1.0f / 128.0f);
        float rx = 1.0f / sqrtf(vx + 1e-5f);
        float lnx0 = dx0 * rx * gxg0 + gxb0;
        float lnx1 = dx1 * rx * gxg1 + gxb1;
        // wait for wave1's lnh_t
        while (vsmi[OFF_FLAGA + t] == 0) __builtin_amdgcn_s_sleep(1);
        float lnh0 = sm[OFF_LNH + tid];
        float lnh1 = sm[OFF_LNH + 64 + tid];
        float g0 = lnx0 + lnh0 + lb0;      // gate[tid]     (i|f half)
        float g1 = lnx1 + lnh1 + lb1;      // gate[tid+64]  (o|u half)
        float fq = __shfl(g0, tid + 32);
        float uq = __shfl(g1, tid + 32);
        float cN = sigm(fq) * creg + sigm(g0) * tanhf(uq);
        float hN = sigm(g1) * tanhf(cN);
        creg = cN;                          // garbage lanes>=32, never read
        if (tid < 32) sm[OFF_H + t * 32 + tid] = hN;
        lds_fence();
        if (tid == 0) smi[OFF_FLAGB + t] = 1;
        #pragma unroll
        for (int k = 0; k < 32; ++k) xf[k] = __shfl(hN, k);
      }
    } else if (tid < 128) {
      // ======== wave1: beta gh-side ========
      const int l = tid - 64;
      float whr0[32], whr1[32];
      #pragma unroll
      for (int k = 0; k < 32; ++k) {
        whr0[k] = wh[k * 128 + l];
        whr1[k] = wh[k * 128 + 64 + l];
      }
      #pragma unroll
      for (int k = 0; k < 32; ++k) asm volatile("" : "+v"(whr0[k]), "+v"(whr1[k]));
      const float ghg0 = ln_gh[l], ghg1 = ln_gh[l + 64];
      const float ghb0 = ln_bh[l], ghb1 = ln_bh[l + 64];

      #pragma unroll 1
      for (int t = 0; t < T_; ++t) {
        float b0 = 0.f, b1 = 0.f;
        if (t > 0) {
          while (vsmi[OFF_FLAGB + (t - 1)] == 0) __builtin_amdgcn_s_sleep(1);
          float hr[32];
          #pragma unroll
          for (int r = 0; r < 8; ++r) {
            float4 v = *(const float4*)&sm[OFF_H + (t - 1) * 32 + r * 4];
            hr[r*4] = v.x; hr[r*4+1] = v.y; hr[r*4+2] = v.z; hr[r*4+3] = v.w;
          }
          #pragma unroll
          for (int k = 0; k < 32; ++k) { b0 += hr[k] * whr0[k]; b1 += hr[k] * whr1[k]; }
        }
        float sh = b0 + b1;
        for (int off = 32; off; off >>= 1) sh += __shfl_down(sh, off);
        float mh2 = __shfl(sh, 0) * (1.0f / 128.0f);
        float dh0 = b0 - mh2, dh1 = b1 - mh2;
        float ssh = dh0 * dh0 + dh1 * dh1;
        for (int off = 32; off; off >>= 1) ssh += __shfl_down(ssh, off);
        float vh = __shfl(ssh, 0) * (1.0f / 128.0f);
        float rh = 1.0f / sqrtf(vh + 1e-5f);
        sm[OFF_LNH + l]      = dh0 * rh * ghg0 + ghb0;
        sm[OFF_LNH + 64 + l] = dh1 * rh * ghg1 + ghb1;
        lds_fence();
        if (l == 0) smi[OFF_FLAGA + t] = 1;
      }
    } else {
      // ======== waves 2-3: zero key row + gumbel prefill chunks 0,1 ========
      const int L2 = tid - 128;                       // 0..127
      if (L2 < 32) sm[OFF_KEY + L2 * KROW + N_] = 0.f;
      #pragma unroll 1
      for (int cc = 0; cc < 2; ++cc) {
        const int gb = OFF_G + cc * (CS * 516);
        #pragma unroll 1
        for (int ii = 0; ii < 16; ++ii) {
          const int idx = ii * 128 + L2;              // 0..2047
          const int tl = idx >> 9, n = idx & 511;
          const int t = cc * CS + tl;
          sm[gb + tl * 516 + n] = gumbel_draw(sk.k[2*t], sk.k[2*t+1], b, n);
        }
        if (L2 < CS) {
          const int t = cc * CS + L2;
          sm[gb + L2 * 516 + N_] = gumbel_draw(sk.k[2*t], sk.k[2*t+1], b, N_);
        }
      }
    }
  } else {
    // ======== waves 4-7: key GEMM (2 rows/lane, pipelined gathers) ========
    const int i = tid - 256;                          // 0..255
    const float4* kw4 = (const float4*)key_w;
    #pragma unroll 1
    for (int rnd = 0; rnd < 2; ++rnd) {
      const int n = i + rnd * 256;
      const float4* er = (const float4*)(ent + ((size_t)b * N_ + n) * 256);
      float acc[32];
      #pragma unroll
      for (int c = 0; c < 32; ++c) acc[c] = 0.f;
      #pragma unroll 4
      for (int k4 = 0; k4 < 64; ++k4) {
        float4 ev = er[k4];
        float e4[4] = {ev.x, ev.y, ev.z, ev.w};
        #pragma unroll
        for (int j = 0; j < 4; ++j) {
          const int k = k4 * 4 + j;
          #pragma unroll
          for (int c4 = 0; c4 < 8; ++c4) {
            float4 w = kw4[k * 8 + c4];               // wave-uniform
            acc[c4*4+0] += e4[j] * w.x;
            acc[c4*4+1] += e4[j] * w.y;
            acc[c4*4+2] += e4[j] * w.z;
            acc[c4*4+3] += e4[j] * w.w;
          }
        }
      }
      #pragma unroll
      for (int c = 0; c < 32; ++c)
        sm[OFF_KEY + c * KROW + n] = acc[c] + key_b[c];
    }
  }
  __syncthreads();                                    // bar2: H, key, G[0,1] ready

  // ======== pre-pipeline: wave0 mask state; workers kr regs + Q(0) ========
  auto qprep = [&](int cc, int qs) {
    const int qb = OFF_Q + qs * (CS * 516);
    #pragma unroll 1
    for (int tl = 0; tl < CS; ++tl) {
      const int hb = OFF_H + (cc * CS + tl) * 32;
      float hv[32];
      #pragma unroll
      for (int r = 0; r < 8; ++r) {
        float4 v = *(const float4*)&sm[hb + r * 4];
        hv[r*4] = v.x; hv[r*4+1] = v.y; hv[r*4+2] = v.z; hv[r*4+3] = v.w;
      }
      float a0 = 0.f;
      #pragma unroll
      for (int k = 0; k < 32; ++k) a0 += hv[k] * kr0[k];
      sm[qb + tl * 516 + L] = a0 * (1.0f / 32.0f);
      if (L < 64) {
        float a1 = 0.f;
        #pragma unroll
        for (int k = 0; k < 32; ++k) a1 += hv[k] * kr1[k];
        sm[qb + tl * 516 + L + 448] = a1 * (1.0f / 32.0f);
      }
    }
  };
  auto gprep = [&](int cc, int gs) {
    const int gb = OFF_G + gs * (CS * 516);
    #pragma unroll 1
    for (int ii = 0; ii < 5; ++ii) {
      const int idx = ii * 448 + L;
      if (idx < CS * 512) {
        const int tl = idx >> 9, n = idx & 511;
        const int t = cc * CS + tl;
        sm[gb + tl * 516 + n] = gumbel_draw(sk.k[2*t], sk.k[2*t+1], b, n);
      }
    }
    if (L < CS) {
      const int t = cc * CS + L;
      sm[gb + L * 516 + N_] = gumbel_draw(sk.k[2*t], sk.k[2*t+1], b, N_);
    }
  };

  if (tid < 64) {
    #pragma unroll
    for (int j = 0; j < 8; ++j) {
      mreg[j] = aum[(size_t)b * N_ + tid + 64 * j];
      ureg[j] = 0.f;
    }
  } else {
    #pragma unroll
    for (int c = 0; c < 32; ++c) kr0[c] = sm[OFF_KEY + c * KROW + L];
    if (L < 65) {
      #pragma unroll
      for (int c = 0; c < 32; ++c) kr1[c] = sm[OFF_KEY + c * KROW + L + 448];
    }
    qprep(0, 0);
  }
  bar_lds();

  // ======== pipelined sampling: wave0 samples c || workers prep Q(c+1), G(c+2) ========
  for (int c = 0; c < NCH; ++c) {
    if (tid < 64) {
      const int qbase = OFF_Q + (c & 1) * (CS * 516);
      const int gbase = OFF_G + (c % 3) * (CS * 516);
      #pragma unroll 1
      for (int tl = 0; tl < CS; ++tl) {
        const int t = c * CS + tl;
        float* lrow = out_logits + ((size_t)t * B_ + b) * NP_;
        float bv = 0.f; int bi = 0;
        #pragma unroll
        for (int j = 0; j < 8; ++j) {
          const int n = tid + 64 * j;
          float q = sm[qbase + tl * 516 + n] - (1.0f - mreg[j]) * NEGC;
          lrow[n] = q;
          float v = q / temp + sm[gbase + tl * 516 + n];
          if (j == 0) { bv = v; bi = n; }
          else if (v > bv) { bv = v; bi = n; }
        }
        if (tid == 0) {
          float q = -(1.0f - m512) * NEGC;   // zero key row: dot == 0
          lrow[N_] = q;
          float v = q / temp + sm[gbase + tl * 516 + N_];
          if (v > bv) { bv = v; bi = N_; }
        }
        for (int off = 32; off; off >>= 1) {
          float ov = __shfl_down(bv, off);
          int   oi = __shfl_down(bi, off);
          if (ov > bv || (ov == bv && oi < bi)) { bv = ov; bi = oi; }
        }
        const int sel_i = __shfl(bi, 0);
        const int active = !done_reg;
        const int is_end = (sel_i == N_);
        if (tid == 0) out_valid[(size_t)t * B_ + b] = active ? 1.0f : 0.0f;
        if (active && !is_end) {
          #pragma unroll
          for (int j = 0; j < 8; ++j)
            if (tid + 64 * j == sel_i) { mreg[j] = 0.0f; ureg[j] = 1.0f; }
        }
        if (active && is_end) done_reg = 1;
      }
    } else {
      if (c + 1 < NCH) qprep(c + 1, (c + 1) & 1);
      if (c + 2 < NCH) gprep(c + 2, (c + 2) % 3);
    }
    bar_lds();
  }

  // wave0 publishes units
  if (tid < 64) {
    #pragma unroll
    for (int j = 0; j < 8; ++j) sm[OFF_UNITS + tid + 64 * j] = ureg[j];
    if (tid == 0) sm[OFF_UNITS + N_] = 0.f;
  }
  __syncthreads();

  // ======== epilogue: emb_sel & final ========
  {
    const int g = tid >> 5, cc = tid & 31;
    float p = 0.f;
    const int n0 = g * 32;
    for (int nn = 0; nn < 32; ++nn) {
      const int n = n0 + nn;
      p += sm[OFF_UNITS + n] * sm[OFF_KEY + cc * KROW + n];
    }
    if (g == 15) p += sm[OFF_UNITS + N_] * sm[OFF_KEY + cc * KROW + N_];
    sm[OFF_PART + g * 32 + cc] = p;
  }
  for (int n = tid; n < NP_; n += 512) out_units[(size_t)b * NP_ + n] = sm[OFF_UNITS + n];
  __syncthreads();
  if (tid < 32) {
    float s = 0.f;
    #pragma unroll
    for (int g = 0; g < 16; ++g) s += sm[OFF_PART + g * 32 + tid];
    sm[OFF_ES + tid] = s / 513.0f;
  }
  __syncthreads();
  {
    const float* e = emb + (size_t)b * 1024;
    for (int d = tid; d < 1024; d += 512) {
      float a = 0.f;
      #pragma unroll
      for (int k = 0; k < 32; ++k) a += sm[OFF_ES + k] * emb_w[k * 1024 + d];
      out_final[(size_t)b * 1024 + d] = e[d] + a + emb_b[d];
    }
  }
}

extern "C" void kernel_launch(void* const* d_in, const int* in_sizes, int n_in,
                              void* d_out, int out_size, void* d_ws, size_t ws_size,
                              hipStream_t stream) {
  (void)in_sizes; (void)n_in; (void)d_ws; (void)ws_size; (void)out_size;
  const float* emb    = (const float*)d_in[0];
  const float* autm   = (const float*)d_in[1];
  const float* aum    = (const float*)d_in[2];
  const float* ent    = (const float*)d_in[3];
  const float* temp   = (const float*)d_in[4];
  const float* key_w  = (const float*)d_in[5];
  const float* key_b  = (const float*)d_in[6];
  const float* func_w = (const float*)d_in[7];
  const float* func_b = (const float*)d_in[8];
  const float* fc1_w  = (const float*)d_in[9];
  const float* fc1_b  = (const float*)d_in[10];
  const float* fc2_w  = (const float*)d_in[11];
  const float* fc2_b  = (const float*)d_in[12];
  const float* emb_w  = (const float*)d_in[13];
  const float* emb_b  = (const float*)d_in[14];
  const float* wx     = (const float*)d_in[15];
  const float* wh     = (const float*)d_in[16];
  const float* lb     = (const float*)d_in[17];
  const float* gxg    = (const float*)d_in[18];
  const float* gxb    = (const float*)d_in[19];
  const float* ghg    = (const float*)d_in[20];
  const float* ghb    = (const float*)d_in[21];
  float* out = (float*)d_out;

  // output layout: logits[64,256,513] | valid[64,256] | units[256,513] | final[256,1024]
  const size_t OFF_V = (size_t)T_ * B_ * NP_;
  const size_t OFF_U = OFF_V + (size_t)T_ * B_;
  const size_t OFF_F = OFF_U + (size_t)B_ * NP_;

  SkKeys sk = compute_chain();

  suh_fused<<<dim3(B_), dim3(512), LDS_FLOATS * sizeof(float), stream>>>(
      emb, autm, aum, ent, temp, key_w, key_b, func_w, func_b,
      fc1_w, fc1_b, fc2_w, fc2_b, emb_w, emb_b,
      wx, wh, lb, gxg, gxb, ghg, ghb,
      out, out + OFF_V, out + OFF_U, out + OFF_F, sk);
}